// Round 2
// baseline (109.645 us; speedup 1.0000x reference)
//
#include <hip/hip_runtime.h>

#define B_SZ 16
#define T_SZ 512
#define D_SZ 384
#define MAX_DUR 8
#define OUT_LEN (T_SZ * (MAX_DUR - 1))   // 3584
#define D4 (D_SZ / 4)                    // 96
#define TOTAL4 (B_SZ * OUT_LEN * D4)     // 5,505,024

// Kernel A: per-batch masked inclusive scan of ds + searchsorted(csum, t_out, 'right')
// One block per batch row. csum lives in LDS (512 ints = 2KB).
// Writes idx[b*OUT_LEN + j] = source frame index, or -1 if j >= total (pad).
__global__ void __launch_bounds__(T_SZ) scan_search_kernel(
    const int* __restrict__ ds,
    const int* __restrict__ ilens,
    int* __restrict__ idx_out)
{
    __shared__ int s[T_SZ];
    const int b = blockIdx.x;
    const int t = threadIdx.x;
    const int ilen = ilens[b];

    int val = (t < ilen) ? ds[b * T_SZ + t] : 0;
    s[t] = val;
    __syncthreads();

    // Hillis-Steele inclusive scan over 512 elements (9 steps, double-barrier)
    #pragma unroll
    for (int off = 1; off < T_SZ; off <<= 1) {
        int add = (t >= off) ? s[t - off] : 0;
        __syncthreads();
        s[t] += add;
        __syncthreads();
    }

    const int total = s[T_SZ - 1];

    // 3584 searches, 7 per thread. searchsorted has 513 possible results
    // (0..512) -> a fixed 9-step bisection is one short (R0 bug). Use the
    // terminating while-loop form: lo = first index with s[lo] > k.
    for (int k = t; k < OUT_LEN; k += T_SZ) {
        int lo = 0, hi = T_SZ;
        while (lo < hi) {
            int mid = (lo + hi) >> 1;
            if (s[mid] <= k) lo = mid + 1; else hi = mid;
        }
        int idx = lo < (T_SZ - 1) ? lo : (T_SZ - 1);
        idx_out[b * OUT_LEN + k] = (k < total) ? idx : -1;
    }
}

// Kernel B: one thread per output float4. idx[row] is broadcast-cached
// (row changes every 96 lanes). Coalesced 16B/lane writes; xs reads hit L2.
__global__ void __launch_bounds__(256) gather_kernel(
    const float4* __restrict__ xs,
    const int* __restrict__ idx,
    float4* __restrict__ out)
{
    int gid = blockIdx.x * 256 + threadIdx.x;
    if (gid >= TOTAL4) return;

    int row = gid / D4;          // magic-mul by compiler
    int d4  = gid - row * D4;
    int i   = idx[row];

    float4 v;
    if (i < 0) {
        v.x = 0.f; v.y = 0.f; v.z = 0.f; v.w = 0.f;
    } else {
        int b = row / OUT_LEN;
        v = xs[(b * T_SZ + i) * D4 + d4];
    }
    out[gid] = v;
}

extern "C" void kernel_launch(void* const* d_in, const int* in_sizes, int n_in,
                              void* d_out, int out_size, void* d_ws, size_t ws_size,
                              hipStream_t stream) {
    const float* xs    = (const float*)d_in[0];
    const int*   ds    = (const int*)d_in[1];
    const int*   ilens = (const int*)d_in[2];
    float*       out   = (float*)d_out;
    int*         idx   = (int*)d_ws;   // B*OUT_LEN ints = 229,376 bytes

    scan_search_kernel<<<B_SZ, T_SZ, 0, stream>>>(ds, ilens, idx);

    constexpr int nblk = (TOTAL4 + 255) / 256;  // 21504
    gather_kernel<<<nblk, 256, 0, stream>>>(
        (const float4*)xs, idx, (float4*)out);
}